// Round 1
// baseline (102814.832 us; speedup 1.0000x reference)
//
#include <hip/hip_runtime.h>
#include <cmath>

#define SEQ  256
#define BATCH 128
#define FEAT 512
#define HID  1024
#define NL   3
#define GATES 4096
#define BH (BATCH*HID)

__device__ __forceinline__ float sigf(float x) { return 1.0f/(1.0f + expf(-x)); }

// Fused gates GEMM + LSTM cell.
// Computes gates[m, g*1024 + n] = A1[m,:K1] @ W1[g*1024+n, :K1]^T
//                               + hprev[m,:1024] @ Whh[g*1024+n, :1024]^T + bias
// for m in [m0, m0+64), n in [n0, n0+16), all 4 gates g, then applies the
// LSTM cell: c = sig(f)*c + sig(i)*tanh(g); h = sig(o)*tanh(c).
// Tile: TM=64 rows x (TN=16 cols x 4 gates). Grid (2, 64) = 128 blocks.
__global__ __launch_bounds__(256)
void gates_cell_kernel(const float* __restrict__ A1, int K1,
                       const float* __restrict__ W1,     // [4096, K1]
                       const float* __restrict__ hprev,  // [B, H]
                       const float* __restrict__ Whh,    // [4096, H]
                       const float* __restrict__ bih,    // [4096] (layer slice)
                       const float* __restrict__ bhh,    // [4096]
                       float* __restrict__ cbuf,         // [B, H] in-place
                       float* __restrict__ hnew)         // [B, H]
{
  const int m0 = blockIdx.x * 64;
  const int n0 = blockIdx.y * 16;
  __shared__ float As[32][68];   // As[kk][m], pad to 68 (mult of 4 for float4 align)
  __shared__ float Bs[32][68];   // Bs[kk][(n<<2)|g]  gate-interleaved
  const int tid = threadIdx.x;
  const int tm = tid & 15;       // 16 m-groups of 4 rows
  const int tn = tid >> 4;       // 16 n columns
  const int r  = tid >> 3;       // staging row 0..31
  const int kq = (tid & 7) << 2; // staging k chunk
  float acc[4][4] = {};          // acc[mi][gate]
  const int Ktot = K1 + HID;
  for (int k0 = 0; k0 < Ktot; k0 += 32) {
    const float* Ap; const float* Wp; int k, lda;
    if (k0 < K1) { Ap = A1;    Wp = W1;  k = k0;       lda = K1;  }
    else         { Ap = hprev; Wp = Whh; k = k0 - K1;  lda = HID; }
    #pragma unroll
    for (int hh = 0; hh < 2; ++hh) {
      const int m = r + hh*32;  // 0..63
      const float4 v = *(const float4*)(Ap + (size_t)(m0+m)*lda + k + kq);
      As[kq+0][m]=v.x; As[kq+1][m]=v.y; As[kq+2][m]=v.z; As[kq+3][m]=v.w;
      const int g = m >> 4, n = m & 15;
      const float4 w = *(const float4*)(Wp + (size_t)(g*HID + n0 + n)*lda + k + kq);
      const int bc = (n<<2)|g;
      Bs[kq+0][bc]=w.x; Bs[kq+1][bc]=w.y; Bs[kq+2][bc]=w.z; Bs[kq+3][bc]=w.w;
    }
    __syncthreads();
    #pragma unroll
    for (int kk = 0; kk < 32; ++kk) {
      const float4 av = *(const float4*)&As[kk][tm<<2];
      const float4 bv = *(const float4*)&Bs[kk][tn<<2];
      const float a_[4] = {av.x, av.y, av.z, av.w};
      const float b_[4] = {bv.x, bv.y, bv.z, bv.w};
      #pragma unroll
      for (int mi=0; mi<4; ++mi)
        #pragma unroll
        for (int gi=0; gi<4; ++gi)
          acc[mi][gi] = fmaf(a_[mi], b_[gi], acc[mi][gi]);
    }
    __syncthreads();
  }
  const int ncol = n0 + tn;
  const float bi = bih[ncol]        + bhh[ncol];
  const float bf = bih[HID+ncol]    + bhh[HID+ncol];
  const float bg = bih[2*HID+ncol]  + bhh[2*HID+ncol];
  const float bo = bih[3*HID+ncol]  + bhh[3*HID+ncol];
  #pragma unroll
  for (int mi=0; mi<4; ++mi) {
    const int mrow = m0 + (tm<<2) + mi;
    const float iv = sigf(acc[mi][0] + bi);
    const float fv = sigf(acc[mi][1] + bf);
    const float gv = tanhf(acc[mi][2] + bg);
    const float ov = sigf(acc[mi][3] + bo);
    const size_t idx = (size_t)mrow*HID + ncol;
    const float cn = fv*cbuf[idx] + iv*gv;
    cbuf[idx] = cn;
    hnew[idx] = ov * tanhf(cn);
  }
}

// C[m, n] = (A1[m,:] (+ A2[m,:])) @ W[n,:]^T + bias[n]
// Tile 32x32, grid (4, 32) = 128 blocks.
__global__ __launch_bounds__(256)
void linear_kernel(const float* __restrict__ A1,
                   const float* __restrict__ A2,   // nullable residual
                   const float* __restrict__ W,    // [1024, 1024]
                   const float* __restrict__ bias, // [1024]
                   float* __restrict__ Cout)       // [B, H]
{
  const int m0 = blockIdx.x * 32;
  const int n0 = blockIdx.y * 32;
  __shared__ float As[32][34];
  __shared__ float Bs[32][34];
  const int tid = threadIdx.x;
  const int tm = tid & 15;
  const int tn = tid >> 4;
  const int r  = tid >> 3;        // 0..31
  const int kq = (tid & 7) << 2;
  float acc[2][2] = {};
  for (int k0 = 0; k0 < HID; k0 += 32) {
    float4 v = *(const float4*)(A1 + (size_t)(m0+r)*HID + k0 + kq);
    if (A2) {
      const float4 u = *(const float4*)(A2 + (size_t)(m0+r)*HID + k0 + kq);
      v.x+=u.x; v.y+=u.y; v.z+=u.z; v.w+=u.w;
    }
    As[kq+0][r]=v.x; As[kq+1][r]=v.y; As[kq+2][r]=v.z; As[kq+3][r]=v.w;
    const float4 w = *(const float4*)(W + (size_t)(n0+r)*HID + k0 + kq);
    Bs[kq+0][r]=w.x; Bs[kq+1][r]=w.y; Bs[kq+2][r]=w.z; Bs[kq+3][r]=w.w;
    __syncthreads();
    #pragma unroll
    for (int kk=0; kk<32; ++kk) {
      const float2 a = *(const float2*)&As[kk][tm<<1];
      const float2 b = *(const float2*)&Bs[kk][tn<<1];
      acc[0][0] = fmaf(a.x, b.x, acc[0][0]);
      acc[0][1] = fmaf(a.x, b.y, acc[0][1]);
      acc[1][0] = fmaf(a.y, b.x, acc[1][0]);
      acc[1][1] = fmaf(a.y, b.y, acc[1][1]);
    }
    __syncthreads();
  }
  const int mrow = m0 + (tm<<1);
  const int ncol = n0 + (tn<<1);
  #pragma unroll
  for (int mi=0; mi<2; ++mi) {
    float2 o;
    o.x = acc[mi][0] + bias[ncol];
    o.y = acc[mi][1] + bias[ncol+1];
    *(float2*)(Cout + (size_t)(mrow+mi)*HID + ncol) = o;
  }
}

extern "C" void kernel_launch(void* const* d_in, const int* in_sizes, int n_in,
                              void* d_out, int out_size, void* d_ws, size_t ws_size,
                              hipStream_t stream) {
  const float* x    = (const float*)d_in[0];  // [256,128,512]
  const float* Wih0 = (const float*)d_in[1];  // [4096,512]
  const float* Wihr = (const float*)d_in[2];  // [2,4096,1024]
  const float* Whh  = (const float*)d_in[3];  // [3,4096,1024]
  const float* bih  = (const float*)d_in[4];  // [3,4096]
  const float* bhh  = (const float*)d_in[5];  // [3,4096]
  const float* Wout = (const float*)d_in[6];  // [1024,1024]
  const float* bout = (const float*)d_in[7];  // [1024]
  float* out = (float*)d_out;

  float* ws   = (float*)d_ws;
  float* hbuf = ws;             // [2][3][B][H] ping-pong
  float* cbuf = ws + 6*(size_t)BH;  // [3][B][H] in-place
  float* ftA  = ws + 9*(size_t)BH;  // [B][H]
  float* ftB  = ws + 10*(size_t)BH; // [B][H]

  // zero h (both parities) and c each call — harness does not re-poison
  hipMemsetAsync(ws, 0, 9*(size_t)BH*sizeof(float), stream);

  const dim3 gGrid(2, 64), lGrid(4, 32);
  for (int t = 0; t < SEQ; ++t) {
    const int p = t & 1;
    float* hp = hbuf + (size_t)p*3*BH;
    float* hn = hbuf + (size_t)(1-p)*3*BH;
    const float* xt = x + (size_t)t*BATCH*FEAT;

    // layer 0
    gates_cell_kernel<<<gGrid, 256, 0, stream>>>(
        xt, FEAT, Wih0, hp, Whh, bih, bhh, cbuf, hn);
    linear_kernel<<<lGrid, 256, 0, stream>>>(hn, nullptr, Wout, bout, ftA);
    // layer 1
    gates_cell_kernel<<<gGrid, 256, 0, stream>>>(
        ftA, HID, Wihr, hp + BH, Whh + (size_t)GATES*HID,
        bih + GATES, bhh + GATES, cbuf + BH, hn + BH);
    linear_kernel<<<lGrid, 256, 0, stream>>>(hn + BH, ftA, Wout, bout, ftB);
    // layer 2
    gates_cell_kernel<<<gGrid, 256, 0, stream>>>(
        ftB, HID, Wihr + (size_t)GATES*HID, hp + 2*BH, Whh + 2*(size_t)GATES*HID,
        bih + 2*GATES, bhh + 2*GATES, cbuf + 2*BH, hn + 2*BH);
    linear_kernel<<<lGrid, 256, 0, stream>>>(hn + 2*BH, ftB, Wout, bout,
                                             out + (size_t)t*BH);
  }
}

// Round 2
// 23758.577 us; speedup vs baseline: 4.3275x; 4.3275x over previous
//
#include <hip/hip_runtime.h>
#include <cmath>

#define SEQ  256
#define BATCH 128
#define FEAT 512
#define HID  1024
#define G4   4096
#define BH (BATCH*HID)

typedef __attribute__((ext_vector_type(8))) __bf16 bf16x8;
typedef __attribute__((ext_vector_type(4))) float f32x4;

__device__ __forceinline__ unsigned short bf16_rne(float f) {
  unsigned int u = __float_as_uint(f);
  unsigned int r = u + 0x7FFFu + ((u >> 16) & 1u);
  return (unsigned short)(r >> 16);
}
__device__ __forceinline__ float bf16_tof(unsigned short s) {
  return __uint_as_float(((unsigned int)s) << 16);
}

// f32 -> (hi, lo) bf16 split, 4 elems/thread, grid-stride
__global__ __launch_bounds__(256)
void convert_hilo(const float* __restrict__ src, unsigned short* __restrict__ hi,
                  unsigned short* __restrict__ lo, int n4) {
  for (int i = blockIdx.x*256 + threadIdx.x; i < n4; i += gridDim.x*256) {
    const float4 v = ((const float4*)src)[i];
    ushort4 h, l;
    h.x = bf16_rne(v.x); l.x = bf16_rne(v.x - bf16_tof(h.x));
    h.y = bf16_rne(v.y); l.y = bf16_rne(v.y - bf16_tof(h.y));
    h.z = bf16_rne(v.z); l.z = bf16_rne(v.z - bf16_tof(h.z));
    h.w = bf16_rne(v.w); l.w = bf16_rne(v.w - bf16_tof(h.w));
    ((ushort4*)hi)[i] = h; ((ushort4*)lo)[i] = l;
  }
}

// Split-precision bf16 MFMA GEMM: part[z][m][n] (+)= sum over k-slice z of
//   Acat[m,:] @ Wcat[n,:]^T   where Acat = [A1 | A2] (K1 + K2 cols),
// computed as 3 products: Ah*Wh + Al*Wh + Ah*Wl (fp32 accum).
// Tile BM=64 x BN=64 x BK=64; 4 waves of 32x32 (2x2 16x16 frags each).
// Grid: (BATCH/64, Ntot/64, KS); Kper = (K1+K2)/KS, multiple of 64;
// K1 % 64 == 0 so chunks never straddle the segment boundary.
__global__ __launch_bounds__(256)
void gemm_split(const unsigned short* __restrict__ A1h, const unsigned short* __restrict__ A1l, int K1,
                const unsigned short* __restrict__ A2h, const unsigned short* __restrict__ A2l, int K2,
                const unsigned short* __restrict__ W1h, const unsigned short* __restrict__ W1l,
                const unsigned short* __restrict__ W2h, const unsigned short* __restrict__ W2l,
                float* __restrict__ part, int Ntot, int Kper)
{
  __shared__ unsigned short lAh[64][72], lAl[64][72], lWh[64][72], lWl[64][72];
  const int tid  = threadIdx.x;
  const int lane = tid & 63, wave = tid >> 6;
  const int wr = wave >> 1, wc = wave & 1;      // 2x2 wave grid
  const int m0 = blockIdx.x * 64, n0 = blockIdx.y * 64;
  const int kstart = blockIdx.z * Kper;
  f32x4 zero4 = {0.f, 0.f, 0.f, 0.f};
  f32x4 acc[2][2] = {{zero4, zero4}, {zero4, zero4}};
  const int nch = Kper >> 6;
  for (int ch = 0; ch < nch; ++ch) {
    const int kg = kstart + (ch << 6);
    const unsigned short *pAh, *pAl, *pWh, *pWl; int sA, sW;
    if (kg < K1) { pAh = A1h + kg; pAl = A1l + kg; sA = K1;
                   pWh = W1h + kg; pWl = W1l + kg; sW = K1; }
    else         { const int k2 = kg - K1;
                   pAh = A2h + k2; pAl = A2l + k2; sA = K2;
                   pWh = W2h + k2; pWl = W2l + k2; sW = K2; }
    __syncthreads();
    #pragma unroll
    for (int hh = 0; hh < 2; ++hh) {
      const int u = tid + (hh << 8);
      const int row = u >> 3, sl = (u & 7) << 3;   // 64 rows x 8 slots of 8 ushorts
      *(int4*)&lAh[row][sl] = *(const int4*)(pAh + (size_t)(m0+row)*sA + sl);
      *(int4*)&lAl[row][sl] = *(const int4*)(pAl + (size_t)(m0+row)*sA + sl);
      *(int4*)&lWh[row][sl] = *(const int4*)(pWh + (size_t)(n0+row)*sW + sl);
      *(int4*)&lWl[row][sl] = *(const int4*)(pWl + (size_t)(n0+row)*sW + sl);
    }
    __syncthreads();
    #pragma unroll
    for (int kk = 0; kk < 64; kk += 32) {
      const int ko = kk + ((lane >> 4) << 3);
      const int ar = (wr << 5) + (lane & 15);
      const int nr = (wc << 5) + (lane & 15);
      const bf16x8 ah0 = *(const bf16x8*)&lAh[ar   ][ko];
      const bf16x8 ah1 = *(const bf16x8*)&lAh[ar+16][ko];
      const bf16x8 al0 = *(const bf16x8*)&lAl[ar   ][ko];
      const bf16x8 al1 = *(const bf16x8*)&lAl[ar+16][ko];
      const bf16x8 bh0 = *(const bf16x8*)&lWh[nr   ][ko];
      const bf16x8 bh1 = *(const bf16x8*)&lWh[nr+16][ko];
      const bf16x8 bl0 = *(const bf16x8*)&lWl[nr   ][ko];
      const bf16x8 bl1 = *(const bf16x8*)&lWl[nr+16][ko];
      acc[0][0] = __builtin_amdgcn_mfma_f32_16x16x32_bf16(ah0, bh0, acc[0][0], 0,0,0);
      acc[0][1] = __builtin_amdgcn_mfma_f32_16x16x32_bf16(ah0, bh1, acc[0][1], 0,0,0);
      acc[1][0] = __builtin_amdgcn_mfma_f32_16x16x32_bf16(ah1, bh0, acc[1][0], 0,0,0);
      acc[1][1] = __builtin_amdgcn_mfma_f32_16x16x32_bf16(ah1, bh1, acc[1][1], 0,0,0);
      acc[0][0] = __builtin_amdgcn_mfma_f32_16x16x32_bf16(al0, bh0, acc[0][0], 0,0,0);
      acc[0][1] = __builtin_amdgcn_mfma_f32_16x16x32_bf16(al0, bh1, acc[0][1], 0,0,0);
      acc[1][0] = __builtin_amdgcn_mfma_f32_16x16x32_bf16(al1, bh0, acc[1][0], 0,0,0);
      acc[1][1] = __builtin_amdgcn_mfma_f32_16x16x32_bf16(al1, bh1, acc[1][1], 0,0,0);
      acc[0][0] = __builtin_amdgcn_mfma_f32_16x16x32_bf16(ah0, bl0, acc[0][0], 0,0,0);
      acc[0][1] = __builtin_amdgcn_mfma_f32_16x16x32_bf16(ah0, bl1, acc[0][1], 0,0,0);
      acc[1][0] = __builtin_amdgcn_mfma_f32_16x16x32_bf16(ah1, bl0, acc[1][0], 0,0,0);
      acc[1][1] = __builtin_amdgcn_mfma_f32_16x16x32_bf16(ah1, bl1, acc[1][1], 0,0,0);
    }
  }
  // C/D layout: col = lane&15, row = (lane>>4)*4 + r   [m89/m91 verified]
  const int rb = (lane >> 4) << 2;
  const int cb = lane & 15;
  float* const pb = part + (size_t)blockIdx.z * BATCH * Ntot;
  #pragma unroll
  for (int mi = 0; mi < 2; ++mi)
    #pragma unroll
    for (int ni = 0; ni < 2; ++ni)
      #pragma unroll
      for (int r = 0; r < 4; ++r) {
        const int row = m0 + (wr<<5) + (mi<<4) + rb + r;
        const int col = n0 + (wc<<5) + (ni<<4) + cb;
        pb[(size_t)row*Ntot + col] = acc[mi][ni][r];
      }
}

// Reduce gates partials + bias, LSTM cell, emit h and s=h(+ft) as bf16 hi/lo.
__global__ __launch_bounds__(256)
void cell_kernel(const float* __restrict__ gpart,  // [2][128][4096]
                 const float* __restrict__ bih, const float* __restrict__ bhh, // layer slices [4096]
                 const float* __restrict__ ftin,   // residual [128][1024] or null
                 float* __restrict__ c,            // [128][1024] layer slice, in-place
                 unsigned short* __restrict__ hh, unsigned short* __restrict__ hl,
                 unsigned short* __restrict__ sh, unsigned short* __restrict__ sl)
{
  const int e = blockIdx.x*256 + threadIdx.x;     // grid 512 -> BH elems
  const int m = e >> 10, n = e & 1023;
  const float* p0 = gpart + (size_t)m*4096 + n;
  const float* p1 = p0 + (size_t)BATCH*4096;
  const float gi = p0[0]    + p1[0]    + bih[n]      + bhh[n];
  const float gf = p0[1024] + p1[1024] + bih[1024+n] + bhh[1024+n];
  const float gg = p0[2048] + p1[2048] + bih[2048+n] + bhh[2048+n];
  const float go = p0[3072] + p1[3072] + bih[3072+n] + bhh[3072+n];
  const float iv = 1.0f/(1.0f+expf(-gi));
  const float fv = 1.0f/(1.0f+expf(-gf));
  const float gv = tanhf(gg);
  const float ov = 1.0f/(1.0f+expf(-go));
  const float cn = fv * c[e] + iv * gv;
  c[e] = cn;
  const float h = ov * tanhf(cn);
  hh[e] = bf16_rne(h); hl[e] = bf16_rne(h - bf16_tof(hh[e]));
  const float s = h + (ftin ? ftin[e] : 0.0f);
  sh[e] = bf16_rne(s); sl[e] = bf16_rne(s - bf16_tof(sh[e]));
}

// Reduce linear partials + b_out -> ft (f32 + bf16 hi/lo) or final output.
__global__ __launch_bounds__(256)
void linreduce_kernel(const float* __restrict__ lpart, // [4][128][1024]
                      const float* __restrict__ bout,
                      float* __restrict__ ftf,
                      unsigned short* __restrict__ fth, unsigned short* __restrict__ ftl,
                      float* __restrict__ outp)        // non-null on last layer
{
  const int e = blockIdx.x*256 + threadIdx.x;
  const int n = e & 1023;
  const float v = lpart[e] + lpart[BH + e] + lpart[2*BH + e] + lpart[3*BH + e] + bout[n];
  if (outp) { outp[e] = v; }
  else {
    ftf[e] = v;
    fth[e] = bf16_rne(v); ftl[e] = bf16_rne(v - bf16_tof(fth[e]));
  }
}

extern "C" void kernel_launch(void* const* d_in, const int* in_sizes, int n_in,
                              void* d_out, int out_size, void* d_ws, size_t ws_size,
                              hipStream_t stream) {
  const float* x    = (const float*)d_in[0];  // [256,128,512]
  const float* Wih0 = (const float*)d_in[1];  // [4096,512]
  const float* Wihr = (const float*)d_in[2];  // [2,4096,1024]
  const float* Whh  = (const float*)d_in[3];  // [3,4096,1024]
  const float* bih  = (const float*)d_in[4];  // [3,4096]
  const float* bhh  = (const float*)d_in[5];  // [3,4096]
  const float* Wout = (const float*)d_in[6];  // [1024,1024]
  const float* bout = (const float*)d_in[7];  // [1024]
  float* out = (float*)d_out;

  char* base = (char*)d_ws;
  size_t off = 0;
  auto alloc = [&](size_t bytes) -> char* {
    char* p = base + off;
    off = (off + bytes + 255) & ~(size_t)255;
    return p;
  };
  float* gpart = (float*)alloc(2ull*BATCH*G4*4);
  float* lpart = (float*)alloc(4ull*BH*4);
  float* cst   = (float*)alloc(3ull*BH*4);
  float* ftf   = (float*)alloc((size_t)BH*4);
  unsigned short* h_hi = (unsigned short*)alloc(3ull*BH*2);
  unsigned short* h_lo = (unsigned short*)alloc(3ull*BH*2);
  unsigned short* s_hi = (unsigned short*)alloc((size_t)BH*2);
  unsigned short* s_lo = (unsigned short*)alloc((size_t)BH*2);
  unsigned short* ft_hi = (unsigned short*)alloc((size_t)BH*2);
  unsigned short* ft_lo = (unsigned short*)alloc((size_t)BH*2);
  unsigned short* Wih0h = (unsigned short*)alloc((size_t)G4*FEAT*2);
  unsigned short* Wih0l = (unsigned short*)alloc((size_t)G4*FEAT*2);
  unsigned short* Wihrh = (unsigned short*)alloc(2ull*G4*HID*2);
  unsigned short* Wihrl = (unsigned short*)alloc(2ull*G4*HID*2);
  unsigned short* Whhh  = (unsigned short*)alloc(3ull*G4*HID*2);
  unsigned short* Whhl  = (unsigned short*)alloc(3ull*G4*HID*2);
  unsigned short* Wouth = (unsigned short*)alloc((size_t)HID*HID*2);
  unsigned short* Woutl = (unsigned short*)alloc((size_t)HID*HID*2);
  const size_t xfull_bytes = 2ull*(size_t)SEQ*BATCH*FEAT*2 + 512;
  const bool xfull = (off + xfull_bytes) <= ws_size;
  unsigned short *x_hi, *x_lo;
  if (xfull) {
    x_hi = (unsigned short*)alloc((size_t)SEQ*BATCH*FEAT*2);
    x_lo = (unsigned short*)alloc((size_t)SEQ*BATCH*FEAT*2);
  } else {
    x_hi = (unsigned short*)alloc((size_t)BATCH*FEAT*2);
    x_lo = (unsigned short*)alloc((size_t)BATCH*FEAT*2);
  }

  // Per-call weight conversion (deterministic, ~0.05 ms)
  convert_hilo<<<1024, 256, 0, stream>>>(Wih0, Wih0h, Wih0l, G4*FEAT/4);
  convert_hilo<<<2048, 256, 0, stream>>>(Wihr, Wihrh, Wihrl, 2*G4*HID/4);
  convert_hilo<<<2048, 256, 0, stream>>>(Whh,  Whhh,  Whhl,  3*G4*HID/4);
  convert_hilo<<<1024, 256, 0, stream>>>(Wout, Wouth, Woutl, HID*HID/4);
  if (xfull)
    convert_hilo<<<2048, 256, 0, stream>>>(x, x_hi, x_lo, SEQ*BATCH*FEAT/4);

  // zero recurrent state each call
  hipMemsetAsync(cst,  0, 3ull*BH*4, stream);
  hipMemsetAsync(h_hi, 0, 3ull*BH*2, stream);
  hipMemsetAsync(h_lo, 0, 3ull*BH*2, stream);

  const dim3 gGrid(2, 64, 2);   // gates: KS=2
  const dim3 lGrid(2, 16, 4);   // linear: KS=4
  for (int t = 0; t < SEQ; ++t) {
    const unsigned short* xth;
    const unsigned short* xtl;
    if (xfull) { xth = x_hi + (size_t)t*BATCH*FEAT; xtl = x_lo + (size_t)t*BATCH*FEAT; }
    else {
      convert_hilo<<<64, 256, 0, stream>>>(x + (size_t)t*BATCH*FEAT, x_hi, x_lo, BATCH*FEAT/4);
      xth = x_hi; xtl = x_lo;
    }
    // ---- layer 0 ----
    gemm_split<<<gGrid, 256, 0, stream>>>(
        xth, xtl, FEAT, h_hi, h_lo, HID,
        Wih0h, Wih0l, Whhh, Whhl, gpart, G4, (FEAT+HID)/2);
    cell_kernel<<<512, 256, 0, stream>>>(gpart, bih, bhh, nullptr,
        cst, h_hi, h_lo, s_hi, s_lo);
    gemm_split<<<lGrid, 256, 0, stream>>>(
        s_hi, s_lo, HID, s_hi, s_lo, 0,
        Wouth, Woutl, Wouth, Woutl, lpart, HID, HID/4);
    linreduce_kernel<<<512, 256, 0, stream>>>(lpart, bout, ftf, ft_hi, ft_lo, nullptr);
    // ---- layer 1 ----
    gemm_split<<<gGrid, 256, 0, stream>>>(
        ft_hi, ft_lo, HID, h_hi + BH, h_lo + BH, HID,
        Wihrh, Wihrl, Whhh + (size_t)G4*HID, Whhl + (size_t)G4*HID,
        gpart, G4, (2*HID)/2);
    cell_kernel<<<512, 256, 0, stream>>>(gpart, bih + G4, bhh + G4, ftf,
        cst + BH, h_hi + BH, h_lo + BH, s_hi, s_lo);
    gemm_split<<<lGrid, 256, 0, stream>>>(
        s_hi, s_lo, HID, s_hi, s_lo, 0,
        Wouth, Woutl, Wouth, Woutl, lpart, HID, HID/4);
    linreduce_kernel<<<512, 256, 0, stream>>>(lpart, bout, ftf, ft_hi, ft_lo, nullptr);
    // ---- layer 2 ----
    gemm_split<<<gGrid, 256, 0, stream>>>(
        ft_hi, ft_lo, HID, h_hi + 2*BH, h_lo + 2*BH, HID,
        Wihrh + (size_t)G4*HID, Wihrl + (size_t)G4*HID,
        Whhh + 2ull*G4*HID, Whhl + 2ull*G4*HID,
        gpart, G4, (2*HID)/2);
    cell_kernel<<<512, 256, 0, stream>>>(gpart, bih + 2*G4, bhh + 2*G4, ftf,
        cst + 2*BH, h_hi + 2*BH, h_lo + 2*BH, s_hi, s_lo);
    gemm_split<<<lGrid, 256, 0, stream>>>(
        s_hi, s_lo, HID, s_hi, s_lo, 0,
        Wouth, Woutl, Wouth, Woutl, lpart, HID, HID/4);
    linreduce_kernel<<<512, 256, 0, stream>>>(lpart, bout, nullptr, nullptr, nullptr,
        out + (size_t)t*BH);
  }
}

// Round 3
// 19476.193 us; speedup vs baseline: 5.2790x; 1.2199x over previous
//
#include <hip/hip_runtime.h>
#include <cmath>

#define SEQ  256
#define BATCH 128
#define FEAT 512
#define HID  1024
#define G4   4096
#define BH (BATCH*HID)
#define KSG 8   // split-K slices, gates GEMM
#define KSL 8   // split-K slices, linear GEMM

typedef __attribute__((ext_vector_type(8))) __bf16 bf16x8;
typedef __attribute__((ext_vector_type(4))) float f32x4;

__device__ __forceinline__ unsigned short bf16_rne(float f) {
  unsigned int u = __float_as_uint(f);
  unsigned int r = u + 0x7FFFu + ((u >> 16) & 1u);
  return (unsigned short)(r >> 16);
}
__device__ __forceinline__ float bf16_tof(unsigned short s) {
  return __uint_as_float(((unsigned int)s) << 16);
}

__device__ __forceinline__ void gload16(const unsigned short* g, unsigned short* l) {
  __builtin_amdgcn_global_load_lds(
      (const __attribute__((address_space(1))) unsigned int*)g,
      (__attribute__((address_space(3))) unsigned int*)l, 16, 0, 0);
}

// f32 -> (hi, lo) bf16 split, 4 elems/thread, grid-stride
__global__ __launch_bounds__(256)
void convert_hilo(const float* __restrict__ src, unsigned short* __restrict__ hi,
                  unsigned short* __restrict__ lo, int n4) {
  for (int i = blockIdx.x*256 + threadIdx.x; i < n4; i += gridDim.x*256) {
    const float4 v = ((const float4*)src)[i];
    ushort4 h, l;
    h.x = bf16_rne(v.x); l.x = bf16_rne(v.x - bf16_tof(h.x));
    h.y = bf16_rne(v.y); l.y = bf16_rne(v.y - bf16_tof(h.y));
    h.z = bf16_rne(v.z); l.z = bf16_rne(v.z - bf16_tof(h.z));
    h.w = bf16_rne(v.w); l.w = bf16_rne(v.w - bf16_tof(h.w));
    ((ushort4*)hi)[i] = h; ((ushort4*)lo)[i] = l;
  }
}

// Split-precision bf16 MFMA GEMM, BM=128 (full batch), BN=128, BK=64.
// part[z][m][n] = sum over k-slice z of Acat[m,:] @ Wcat[n,:]^T  (3-product split).
// 512 threads = 8 waves, wave tile 64x32 (4 m-frags x 2 n-frags of 16x16x32).
// LDS: double-buffered [2][4regions][128][64] ushort = 128 KB, XOR-(row&7)
// 16B-chunk swizzle; staged via global_load_lds w/ pre-swizzled source.
// Grid: (Ntot/128, KS). Kper multiple of 64; K1 % 64 == 0.
__global__ __launch_bounds__(512, 2)
void gemm_split(const unsigned short* __restrict__ A1h, const unsigned short* __restrict__ A1l, int K1,
                const unsigned short* __restrict__ A2h, const unsigned short* __restrict__ A2l, int K2,
                const unsigned short* __restrict__ W1h, const unsigned short* __restrict__ W1l,
                const unsigned short* __restrict__ W2h, const unsigned short* __restrict__ W2l,
                float* __restrict__ part, int Ntot, int Kper)
{
  __shared__ unsigned short lds[2][4][128][64];   // [buf][Ah,Al,Wh,Wl][row][col]
  unsigned short* const lbase = &lds[0][0][0][0];
  const int tid  = threadIdx.x;
  const int lane = tid & 63, wave = tid >> 6;
  const int wr = wave >> 2, wc = wave & 3;        // 2 x 4 wave grid
  const int n0 = blockIdx.x * 128;
  const int kstart = blockIdx.y * Kper;
  const int nch = Kper >> 6;
  const int rl = lane >> 3, cc = lane & 7;
  const int gcol = (cc ^ rl) << 3;                // pre-swizzled 16B chunk (elems)

  auto stage = [&](int ch) {
    const int kg = kstart + (ch << 6);
    const unsigned short *pAh, *pAl, *pWh, *pWl; int sA, sW;
    if (kg < K1) { pAh=A1h+kg; pAl=A1l+kg; sA=K1; pWh=W1h+kg; pWl=W1l+kg; sW=K1; }
    else { const int k2 = kg - K1;
           pAh=A2h+k2; pAl=A2l+k2; sA=K2; pWh=W2h+k2; pWl=W2l+k2; sW=K2; }
    unsigned short* const db = lbase + (size_t)(ch & 1) * 32768;
    #pragma unroll
    for (int q = 0; q < 2; ++q) {
      const int r0 = (wave << 4) + (q << 3);      // 8-row group, wave-uniform
      const int gr = r0 + rl;
      gload16(pAh + (size_t)gr*sA + gcol,       db +          r0*64);
      gload16(pAl + (size_t)gr*sA + gcol,       db +  8192 + r0*64);
      gload16(pWh + (size_t)(n0+gr)*sW + gcol,  db + 16384 + r0*64);
      gload16(pWl + (size_t)(n0+gr)*sW + gcol,  db + 24576 + r0*64);
    }
  };

  f32x4 zero4 = {0.f,0.f,0.f,0.f};
  f32x4 acc[4][2] = {{zero4,zero4},{zero4,zero4},{zero4,zero4},{zero4,zero4}};

  stage(0);
  for (int ch = 0; ch < nch; ++ch) {
    if (ch + 1 < nch) {
      stage(ch + 1);
      asm volatile("s_waitcnt vmcnt(8)" ::: "memory");   // ch's 8 loads done, ch+1's in flight
    } else {
      asm volatile("s_waitcnt vmcnt(0)" ::: "memory");
    }
    __builtin_amdgcn_sched_barrier(0);
    __builtin_amdgcn_s_barrier();
    const unsigned short* const cb = lbase + (size_t)(ch & 1) * 32768;
    #pragma unroll
    for (int kh = 0; kh < 2; ++kh) {
      const int j0 = (kh << 2) + (lane >> 4);     // logical 16B chunk 0..7
      bf16x8 ah[4], al[4], bh[2], bl[2];
      #pragma unroll
      for (int mi = 0; mi < 4; ++mi) {
        const int row = (wr << 6) + (mi << 4) + (lane & 15);
        const int off = row*64 + ((j0 ^ (row & 7)) << 3);
        ah[mi] = *(const bf16x8*)(cb + off);
        al[mi] = *(const bf16x8*)(cb + 8192 + off);
      }
      #pragma unroll
      for (int ni = 0; ni < 2; ++ni) {
        const int wrow = (wc << 5) + (ni << 4) + (lane & 15);
        const int off = wrow*64 + ((j0 ^ (wrow & 7)) << 3);
        bh[ni] = *(const bf16x8*)(cb + 16384 + off);
        bl[ni] = *(const bf16x8*)(cb + 24576 + off);
      }
      #pragma unroll
      for (int mi = 0; mi < 4; ++mi)
        #pragma unroll
        for (int ni = 0; ni < 2; ++ni) {
          acc[mi][ni] = __builtin_amdgcn_mfma_f32_16x16x32_bf16(ah[mi], bh[ni], acc[mi][ni], 0,0,0);
          acc[mi][ni] = __builtin_amdgcn_mfma_f32_16x16x32_bf16(al[mi], bh[ni], acc[mi][ni], 0,0,0);
          acc[mi][ni] = __builtin_amdgcn_mfma_f32_16x16x32_bf16(ah[mi], bl[ni], acc[mi][ni], 0,0,0);
        }
    }
    __builtin_amdgcn_s_barrier();
  }

  // C/D layout: col = lane&15, row = (lane>>4)*4 + r   [m89/m91 verified]
  const int rb  = (lane >> 4) << 2;
  const int cbl = lane & 15;
  float* const pb = part + (size_t)blockIdx.y * BATCH * Ntot;
  #pragma unroll
  for (int mi = 0; mi < 4; ++mi)
    #pragma unroll
    for (int ni = 0; ni < 2; ++ni)
      #pragma unroll
      for (int r = 0; r < 4; ++r) {
        const int row = (wr << 6) + (mi << 4) + rb + r;
        const int col = n0 + (wc << 5) + (ni << 4) + cbl;
        pb[(size_t)row*Ntot + col] = acc[mi][ni][r];
      }
}

// Reduce KSG gates partials + bias, LSTM cell, emit h and s=h(+ft) as bf16 hi/lo.
__global__ __launch_bounds__(256)
void cell_kernel(const float* __restrict__ gpart,  // [KSG][128][4096]
                 const float* __restrict__ bih, const float* __restrict__ bhh,
                 const float* __restrict__ ftin,   // residual [128][1024] or null
                 float* __restrict__ c,            // [128][1024] layer slice, in-place
                 unsigned short* __restrict__ hh, unsigned short* __restrict__ hl,
                 unsigned short* __restrict__ sh, unsigned short* __restrict__ sl)
{
  const int e = blockIdx.x*256 + threadIdx.x;     // grid 512 -> BH elems
  const int m = e >> 10, n = e & 1023;
  const float* p = gpart + (size_t)m*4096 + n;
  float gi = bih[n]        + bhh[n];
  float gf = bih[1024+n]   + bhh[1024+n];
  float gg = bih[2048+n]   + bhh[2048+n];
  float go = bih[3072+n]   + bhh[3072+n];
  #pragma unroll
  for (int z = 0; z < KSG; ++z) {
    gi += p[0]; gf += p[1024]; gg += p[2048]; go += p[3072];
    p += (size_t)BATCH*4096;
  }
  const float iv = 1.0f/(1.0f+expf(-gi));
  const float fv = 1.0f/(1.0f+expf(-gf));
  const float gv = tanhf(gg);
  const float ov = 1.0f/(1.0f+expf(-go));
  const float cn = fv * c[e] + iv * gv;
  c[e] = cn;
  const float h = ov * tanhf(cn);
  hh[e] = bf16_rne(h); hl[e] = bf16_rne(h - bf16_tof(hh[e]));
  const float s = h + (ftin ? ftin[e] : 0.0f);
  sh[e] = bf16_rne(s); sl[e] = bf16_rne(s - bf16_tof(sh[e]));
}

// Reduce KSL linear partials + b_out -> ft (f32 + bf16 hi/lo) or final output.
__global__ __launch_bounds__(256)
void linreduce_kernel(const float* __restrict__ lpart, // [KSL][128][1024]
                      const float* __restrict__ bout,
                      float* __restrict__ ftf,
                      unsigned short* __restrict__ fth, unsigned short* __restrict__ ftl,
                      float* __restrict__ outp)        // non-null on last layer
{
  const int e = blockIdx.x*256 + threadIdx.x;
  const int n = e & 1023;
  float v = bout[n];
  #pragma unroll
  for (int z = 0; z < KSL; ++z) v += lpart[(size_t)z*BH + e];
  if (outp) { outp[e] = v; }
  else {
    ftf[e] = v;
    fth[e] = bf16_rne(v); ftl[e] = bf16_rne(v - bf16_tof(fth[e]));
  }
}

extern "C" void kernel_launch(void* const* d_in, const int* in_sizes, int n_in,
                              void* d_out, int out_size, void* d_ws, size_t ws_size,
                              hipStream_t stream) {
  const float* x    = (const float*)d_in[0];  // [256,128,512]
  const float* Wih0 = (const float*)d_in[1];  // [4096,512]
  const float* Wihr = (const float*)d_in[2];  // [2,4096,1024]
  const float* Whh  = (const float*)d_in[3];  // [3,4096,1024]
  const float* bih  = (const float*)d_in[4];  // [3,4096]
  const float* bhh  = (const float*)d_in[5];  // [3,4096]
  const float* Wout = (const float*)d_in[6];  // [1024,1024]
  const float* bout = (const float*)d_in[7];  // [1024]
  float* out = (float*)d_out;

  char* base = (char*)d_ws;
  size_t off = 0;
  auto alloc = [&](size_t bytes) -> char* {
    char* p = base + off;
    off = (off + bytes + 255) & ~(size_t)255;
    return p;
  };
  float* gpart = (float*)alloc((size_t)KSG*BATCH*G4*4);
  float* lpart = (float*)alloc((size_t)KSL*BH*4);
  float* cst   = (float*)alloc(3ull*BH*4);
  float* ftf   = (float*)alloc((size_t)BH*4);
  unsigned short* h_hi = (unsigned short*)alloc(3ull*BH*2);
  unsigned short* h_lo = (unsigned short*)alloc(3ull*BH*2);
  unsigned short* s_hi = (unsigned short*)alloc((size_t)BH*2);
  unsigned short* s_lo = (unsigned short*)alloc((size_t)BH*2);
  unsigned short* ft_hi = (unsigned short*)alloc((size_t)BH*2);
  unsigned short* ft_lo = (unsigned short*)alloc((size_t)BH*2);
  unsigned short* Wih0h = (unsigned short*)alloc((size_t)G4*FEAT*2);
  unsigned short* Wih0l = (unsigned short*)alloc((size_t)G4*FEAT*2);
  unsigned short* Wihrh = (unsigned short*)alloc(2ull*G4*HID*2);
  unsigned short* Wihrl = (unsigned short*)alloc(2ull*G4*HID*2);
  unsigned short* Whhh  = (unsigned short*)alloc(3ull*G4*HID*2);
  unsigned short* Whhl  = (unsigned short*)alloc(3ull*G4*HID*2);
  unsigned short* Wouth = (unsigned short*)alloc((size_t)HID*HID*2);
  unsigned short* Woutl = (unsigned short*)alloc((size_t)HID*HID*2);
  const size_t xfull_bytes = 2ull*(size_t)SEQ*BATCH*FEAT*2 + 512;
  const bool xfull = (off + xfull_bytes) <= ws_size;
  unsigned short *x_hi, *x_lo;
  if (xfull) {
    x_hi = (unsigned short*)alloc((size_t)SEQ*BATCH*FEAT*2);
    x_lo = (unsigned short*)alloc((size_t)SEQ*BATCH*FEAT*2);
  } else {
    x_hi = (unsigned short*)alloc((size_t)BATCH*FEAT*2);
    x_lo = (unsigned short*)alloc((size_t)BATCH*FEAT*2);
  }

  // Per-call weight conversion
  convert_hilo<<<1024, 256, 0, stream>>>(Wih0, Wih0h, Wih0l, G4*FEAT/4);
  convert_hilo<<<2048, 256, 0, stream>>>(Wihr, Wihrh, Wihrl, 2*G4*HID/4);
  convert_hilo<<<2048, 256, 0, stream>>>(Whh,  Whhh,  Whhl,  3*G4*HID/4);
  convert_hilo<<<1024, 256, 0, stream>>>(Wout, Wouth, Woutl, HID*HID/4);
  if (xfull)
    convert_hilo<<<2048, 256, 0, stream>>>(x, x_hi, x_lo, SEQ*BATCH*FEAT/4);

  // zero recurrent state each call
  hipMemsetAsync(cst,  0, 3ull*BH*4, stream);
  hipMemsetAsync(h_hi, 0, 3ull*BH*2, stream);
  hipMemsetAsync(h_lo, 0, 3ull*BH*2, stream);

  const dim3 gGrid(G4/128, KSG);   // (32, 8)
  const dim3 lGrid(HID/128, KSL);  // (8, 8)
  for (int t = 0; t < SEQ; ++t) {
    const unsigned short* xth;
    const unsigned short* xtl;
    if (xfull) { xth = x_hi + (size_t)t*BATCH*FEAT; xtl = x_lo + (size_t)t*BATCH*FEAT; }
    else {
      convert_hilo<<<64, 256, 0, stream>>>(x + (size_t)t*BATCH*FEAT, x_hi, x_lo, BATCH*FEAT/4);
      xth = x_hi; xtl = x_lo;
    }
    // ---- layer 0 ----
    gemm_split<<<gGrid, 512, 0, stream>>>(
        xth, xtl, FEAT, h_hi, h_lo, HID,
        Wih0h, Wih0l, Whhh, Whhl, gpart, G4, (FEAT+HID)/KSG);
    cell_kernel<<<512, 256, 0, stream>>>(gpart, bih, bhh, nullptr,
        cst, h_hi, h_lo, s_hi, s_lo);
    gemm_split<<<lGrid, 512, 0, stream>>>(
        s_hi, s_lo, HID, s_hi, s_lo, HID,
        Wouth, Woutl, Wouth, Woutl, lpart, HID, HID/KSL);
    linreduce_kernel<<<512, 256, 0, stream>>>(lpart, bout, ftf, ft_hi, ft_lo, nullptr);
    // ---- layer 1 ----
    gemm_split<<<gGrid, 512, 0, stream>>>(
        ft_hi, ft_lo, HID, h_hi + BH, h_lo + BH, HID,
        Wihrh, Wihrl, Whhh + (size_t)G4*HID, Whhl + (size_t)G4*HID,
        gpart, G4, (2*HID)/KSG);
    cell_kernel<<<512, 256, 0, stream>>>(gpart, bih + G4, bhh + G4, ftf,
        cst + BH, h_hi + BH, h_lo + BH, s_hi, s_lo);
    gemm_split<<<lGrid, 512, 0, stream>>>(
        s_hi, s_lo, HID, s_hi, s_lo, HID,
        Wouth, Woutl, Wouth, Woutl, lpart, HID, HID/KSL);
    linreduce_kernel<<<512, 256, 0, stream>>>(lpart, bout, ftf, ft_hi, ft_lo, nullptr);
    // ---- layer 2 ----
    gemm_split<<<gGrid, 512, 0, stream>>>(
        ft_hi, ft_lo, HID, h_hi + 2*BH, h_lo + 2*BH, HID,
        Wihrh + (size_t)G4*HID, Wihrl + (size_t)G4*HID,
        Whhh + 2ull*G4*HID, Whhl + 2ull*G4*HID,
        gpart, G4, (2*HID)/KSG);
    cell_kernel<<<512, 256, 0, stream>>>(gpart, bih + 2*G4, bhh + 2*G4, ftf,
        cst + 2*BH, h_hi + 2*BH, h_lo + 2*BH, s_hi, s_lo);
    gemm_split<<<lGrid, 512, 0, stream>>>(
        s_hi, s_lo, HID, s_hi, s_lo, HID,
        Wouth, Woutl, Wouth, Woutl, lpart, HID, HID/KSL);
    linreduce_kernel<<<512, 256, 0, stream>>>(lpart, bout, nullptr, nullptr, nullptr,
        out + (size_t)t*BH);
  }
}